// Round 1
// 120.470 us; speedup vs baseline: 1.0395x; 1.0395x over previous
//
#include <hip/hip_runtime.h>
#include <math.h>

#define Bq 16
#define Tq 81
#define Dq 128
#define Hq 8
#define BT (Bq*Tq)          // 1296
#define BTD (Bq*Tq*Dq)      // 165888 (out region 0)
#define PS 84               // padded s-stride of P rows in LDS
// ws layout (floats). Q: [b][h][t][d] f32; V: [b][h][s][d] bf16 in V_OFF.
// P region retained in layout but no longer used (K2+K3 fused).
#define P_SZ   (Bq*Tq*Hq*PS)
#define QV_SZ  (BT*Hq*Dq)
#define P_OFF  0
#define Q_OFF  (P_OFF + P_SZ)
#define V_OFF  (Q_OFF + QV_SZ)

#define LSTR 136            // k_qkv LDS row stride (ushorts): 16B-aligned rows

typedef __attribute__((ext_vector_type(8))) short short8;
typedef __attribute__((ext_vector_type(4))) float f32x4;

__device__ __forceinline__ float l1_4(const float4 q, const float4 k) {
    return fabsf(q.x - k.x) + fabsf(q.y - k.y) + fabsf(q.z - k.z) + fabsf(q.w - k.w);
}
__device__ __forceinline__ int imin(int a, int b) { return a < b ? a : b; }
__device__ __forceinline__ unsigned short f2bf(float f) {   // RNE f32 -> bf16
    unsigned u = __float_as_uint(f);
    u += 0x7fffu + ((u >> 16) & 1u);
    return (unsigned short)(u >> 16);
}
__device__ __forceinline__ float bf2f(unsigned short s) {
    return __uint_as_float((unsigned)s << 16);
}

// ---------------------------------------------------------------------------
// K1: QKV GEMM via bf16 MFMA 16x16x32. grid (21, 32), 256 thr = 4 waves.
// Unchanged from the verified R8 kernel.
// ---------------------------------------------------------------------------
__global__ __launch_bounds__(256) void k_qkv_mfma(
    const float* __restrict__ x, const float* __restrict__ wqkv,
    const float* __restrict__ bias, const float* __restrict__ he,
    float* __restrict__ Qo, unsigned short* __restrict__ Vb)
{
    __shared__ unsigned short xs[64 * LSTR];    // 17.4 KB
    __shared__ unsigned short wsh[64 * LSTR];   // 17.4 KB
    const int tid = threadIdx.x;
    const int w = tid >> 6, lane = tid & 63;
    const int ln = lane & 15, quad = lane >> 4;
    const int r0 = blockIdx.x * 64;               // m-row base (bx 0..20)
    const int n0 = blockIdx.y * 64;               // W-row base
    const int h  = blockIdx.y >> 2;
    const int isV = (blockIdx.y >> 1) & 1;
    const int c0 = (blockIdx.y & 1) * 64;

    #pragma unroll
    for (int i = 0; i < 8; ++i) {
        const int idx = tid + i * 256;            // 0..2047
        const int r = idx >> 5, c4 = idx & 31;
        const int gr = imin(r0 + r, BT - 1);      // clamp tail rows
        const float4 v = *(const float4*)(x + (size_t)gr * Dq + c4 * 4);
        ushort4 o;
        o.x = f2bf(v.x); o.y = f2bf(v.y); o.z = f2bf(v.z); o.w = f2bf(v.w);
        *(ushort4*)(&xs[r * LSTR + c4 * 4]) = o;

        const float4 vw = *(const float4*)(wqkv + (size_t)(n0 + r) * Dq + c4 * 4);
        ushort4 ow;
        ow.x = f2bf(vw.x); ow.y = f2bf(vw.y); ow.z = f2bf(vw.z); ow.w = f2bf(vw.w);
        *(ushort4*)(&wsh[r * LSTR + c4 * 4]) = ow;
    }
    __syncthreads();

    const unsigned short* xa = xs + (w * 16 + ln) * LSTR + quad * 8;
    const unsigned short* wb = wsh + ln * LSTR + quad * 8;

    f32x4 acc[4];
    #pragma unroll
    for (int i = 0; i < 4; ++i) acc[i] = (f32x4){0.f, 0.f, 0.f, 0.f};

    #pragma unroll
    for (int kb = 0; kb < Dq; kb += 32) {
        const short8 af = *(const short8*)(xa + kb);
        #pragma unroll
        for (int nt = 0; nt < 4; ++nt) {
            const short8 bf = *(const short8*)(wb + nt * 16 * LSTR + kb);
            acc[nt] = __builtin_amdgcn_mfma_f32_16x16x32_bf16(af, bf, acc[nt], 0, 0, 0);
        }
    }

    const float scale = isV ? he[h] : 1.0f;
    const int gm0 = r0 + w * 16 + quad * 4;
    #pragma unroll
    for (int nt = 0; nt < 4; ++nt) {
        const float bn = bias[n0 + nt * 16 + ln];
        #pragma unroll
        for (int r = 0; r < 4; ++r) {
            const int gm = gm0 + r;
            if (gm < BT) {
                const int bb = gm / 81, tt = gm - bb * 81;
                const size_t o =
                    (((size_t)bb * Hq + h) * Tq + tt) * Dq + c0 + nt * 16 + ln;
                const float val = (acc[nt][r] + bn) * scale;
                if (isV) Vb[o] = f2bf(val);
                else     Qo[o] = val;
            }
        }
    }
}

// ---------------------------------------------------------------------------
// K23 (fused K2+K3): scores + softmax (+ap) + PV + gelu + fanout + residual.
// grid (14, 16) = (t-chunk6, b), block 512 = 8 waves; wave w = head w.
// Theory: the 3-kernel pipeline was overhead/latency-dominated (compute floor
// ~10 us vs 125 us measured); fusing removes one launch, the K2->K3
// dependency drain, and the 3.5 MB P global round-trip.
//
// Phase A: x[b] -> LDS f32 [81][128], 16B-granule XOR swizzle (g ^= s&7) so
//          per-lane row reads in phase B are bank-conflict-free (G4).
// Phase B: lane<->s (s0=lane, s1=64+lane for 17 lanes), wave=head; k=x*wk
//          folded in-loop; q + wk loads are wave-uniform L1 broadcasts; both
//          s-halves share one g-pass (halves q traffic vs old 2-pass K2).
// Phase C: in-register 64-lane softmax (butterfly shfl), P -> LDS [h][6][84],
//          ap fused for b==0.
// Phase D..F: verified K3 tail verbatim (PV with bf16 V, 8-way reduce, gelu,
//          fanout, residual), reading P from LDS instead of global.
// LDS: 41.5 + 16.1 + 24 + 3 = 84.6 KB -> 1 block/CU, 224 blocks.
// ---------------------------------------------------------------------------
__global__ __launch_bounds__(512) void k_attn_out(
    const float* __restrict__ x, const float* __restrict__ Q,
    const float* __restrict__ wk, const float* __restrict__ msk,
    const unsigned short* __restrict__ Vb, const float* __restrict__ fw,
    const float* __restrict__ fb, float* __restrict__ out)
{
    __shared__ float xl[Tq * Dq];            // 41.5 KB, granule-swizzled
    __shared__ float Pl[Hq][6][PS];          // 16.1 KB (336B rows, 16B-aligned)
    __shared__ float bo_part[Hq][6][Dq];     // 24 KB
    __shared__ float zs[6][Dq];              // 3 KB

    const int tid = threadIdx.x;
    const int t0 = blockIdx.x * 6, b = blockIdx.y;
    const int w = tid >> 6, lane = tid & 63;   // w = head

    // ---- Phase A: stage x[b] with 16B-granule XOR swizzle ----
    for (int idx = tid; idx < Tq * 32; idx += 512) {
        const int r = idx >> 5, g = idx & 31;
        const float4 v = *(const float4*)(x + (size_t)(b * Tq + r) * Dq + g * 4);
        *(float4*)(&xl[r * Dq + ((g ^ (r & 7)) << 2)]) = v;
    }
    __syncthreads();

    // ---- Phase B: L1-distance scores for head w, 6 t-rows x 81 s ----
    const int s0 = lane;
    const bool has1 = (lane < Tq - 64);        // 17 lanes own s=64..80
    const int s1 = 64 + lane;
    const int s1c = has1 ? s1 : (Tq - 1);      // clamp for safe LDS read
    int ttv[6];
    const float* qrow[6];
    #pragma unroll
    for (int i = 0; i < 6; ++i) {
        ttv[i] = imin(t0 + i, Tq - 1);
        qrow[i] = Q + (((size_t)b * Hq + w) * Tq + ttv[i]) * Dq;
    }
    const float* wkb = wk + (size_t)w * Dq;

    float acc0[6], acc1[6];
    #pragma unroll
    for (int i = 0; i < 6; ++i) { acc0[i] = 0.f; acc1[i] = 0.f; }

    #pragma unroll 2
    for (int g = 0; g < 32; ++g) {
        const float4 wv = *(const float4*)(wkb + g * 4);            // broadcast
        float4 k0 = *(const float4*)(&xl[s0 * Dq + ((g ^ (s0 & 7)) << 2)]);
        float4 k1 = *(const float4*)(&xl[s1c * Dq + ((g ^ (s1c & 7)) << 2)]);
        k0.x *= wv.x; k0.y *= wv.y; k0.z *= wv.z; k0.w *= wv.w;
        k1.x *= wv.x; k1.y *= wv.y; k1.z *= wv.z; k1.w *= wv.w;
        #pragma unroll
        for (int i = 0; i < 6; ++i) {
            const float4 qv = *(const float4*)(qrow[i] + g * 4);    // broadcast
            acc0[i] += l1_4(qv, k0);
            acc1[i] += l1_4(qv, k1);
        }
    }

    // ---- Phase C: wave softmax + P->LDS + fused ap (b==0) ----
    {
        const float ns = -0.08838834764831845f;   // -1/sqrt(128)
        #pragma unroll
        for (int i = 0; i < 6; ++i) {
            const float v0 = acc0[i] * ns;
            const float v1 = has1 ? acc1[i] * ns : -1e30f;
            float m = fmaxf(v0, v1);
            #pragma unroll
            for (int off = 32; off > 0; off >>= 1)
                m = fmaxf(m, __shfl_xor(m, off));
            const float e0 = __expf(v0 - m);
            const float e1 = has1 ? __expf(v1 - m) : 0.f;
            float ssum = e0 + e1;
            #pragma unroll
            for (int off = 32; off > 0; off >>= 1)
                ssum += __shfl_xor(ssum, off);
            const float rinv = 1.0f / ssum;
            const float* mrow = msk + ((size_t)w * Tq + ttv[i]) * Tq;
            const bool tvalid = (t0 + i) < Tq;
            const float mv0 = mrow[s0];
            const float p0 = e0 * rinv * mv0;
            Pl[w][i][s0] = p0;
            if (b == 0 && tvalid)
                out[BTD + ((size_t)(t0 + i) * Tq + s0) * Hq + w] = p0 - 1.0f + mv0;
            if (has1) {
                const float mv1 = mrow[s1];
                const float p1 = e1 * rinv * mv1;
                Pl[w][i][s1] = p1;
                if (b == 0 && tvalid)
                    out[BTD + ((size_t)(t0 + i) * Tq + s1) * Hq + w] = p1 - 1.0f + mv1;
            }
        }
    }
    __syncthreads();

    // ---- Phase D: PV einsum, bf16 V, s blocked by 4 (verified K3 loop) ----
    {
        const int d0 = lane * 2;
        float2 acc[6];
        #pragma unroll
        for (int i = 0; i < 6; ++i) acc[i] = make_float2(0.f, 0.f);
        const unsigned short* vp = Vb + (((size_t)b * Hq + w) * Tq) * Dq + d0;
        for (int s4 = 0; s4 < 20; ++s4) {
            float4 p[6];
            #pragma unroll
            for (int t = 0; t < 6; ++t)
                p[t] = *(const float4*)(&Pl[w][t][s4 * 4]);
            #pragma unroll
            for (int ss = 0; ss < 4; ++ss) {
                const int s = s4 * 4 + ss;
                const ushort2 uv = *(const ushort2*)(vp + (size_t)s * Dq);
                const float vx = bf2f(uv.x), vy = bf2f(uv.y);
                #pragma unroll
                for (int t = 0; t < 6; ++t) {
                    const float pv = ((const float*)&p[t])[ss];
                    acc[t].x = fmaf(pv, vx, acc[t].x);
                    acc[t].y = fmaf(pv, vy, acc[t].y);
                }
            }
        }
        {   // tail s = 80
            const ushort2 uv = *(const ushort2*)(vp + (size_t)80 * Dq);
            const float vx = bf2f(uv.x), vy = bf2f(uv.y);
            #pragma unroll
            for (int t = 0; t < 6; ++t) {
                const float pv = Pl[w][t][80];
                acc[t].x = fmaf(pv, vx, acc[t].x);
                acc[t].y = fmaf(pv, vy, acc[t].y);
            }
        }
        #pragma unroll
        for (int t = 0; t < 6; ++t) {
            bo_part[w][t][d0]     = acc[t].x;
            bo_part[w][t][d0 + 1] = acc[t].y;
        }
    }
    __syncthreads();

    // ---- Phase E: 8-way head reduce + quick-gelu ----
    for (int idx = tid; idx < 768; idx += 512) {   // 6t x 128d
        const int t = idx >> 7, d = idx & 127;
        float bo = 0.f;
        #pragma unroll
        for (int ww = 0; ww < 8; ++ww) bo += bo_part[ww][t][d];
        const float tt2 = bo + 4.0f;
        const float sg = 1.0f / (1.0f + __expf(-1.702f * tt2));
        zs[t][d] = tt2 * sg - 4.0f;
    }
    __syncthreads();

    // ---- Phase F: fanout + bias + residual ----
    {
        const int n = tid & 127, tg = tid >> 7;   // tg 0..3
        const bool two = (tg < 2);
        const int tB = two ? tg + 4 : tg;          // dummy=tg when !two
        const float* fwr = fw + (size_t)n * Dq;
        const float fbn = fb[n];
        float a0 = 0.f, a1 = 0.f;
        #pragma unroll 8
        for (int k4 = 0; k4 < 32; ++k4) {
            const float4 w4 = *(const float4*)(fwr + k4 * 4);
            const float4 z0 = *(const float4*)(&zs[tg][k4 * 4]);
            const float4 z1 = *(const float4*)(&zs[tB][k4 * 4]);
            a0 += z0.x * w4.x + z0.y * w4.y + z0.z * w4.z + z0.w * w4.w;
            a1 += z1.x * w4.x + z1.y * w4.y + z1.z * w4.z + z1.w * w4.w;
        }
        const int t1 = t0 + tg;
        if (t1 < Tq) {
            const size_t o = ((size_t)b * Tq + t1) * Dq + n;
            out[o] = x[o] + a0 + fbn;
        }
        const int t2 = t0 + tg + 4;
        if (two && t2 < Tq) {
            const size_t o = ((size_t)b * Tq + t2) * Dq + n;
            out[o] = x[o] + a1 + fbn;
        }
    }
}

extern "C" void kernel_launch(void* const* d_in, const int* in_sizes, int n_in,
                              void* d_out, int out_size, void* d_ws, size_t ws_size,
                              hipStream_t stream) {
    const float* x        = (const float*)d_in[0];
    const float* msk      = (const float*)d_in[1];
    const float* wqkv_w   = (const float*)d_in[2];
    const float* wqkv_b   = (const float*)d_in[3];
    const float* wk_w     = (const float*)d_in[4];
    const float* fanout_w = (const float*)d_in[5];
    const float* fanout_b = (const float*)d_in[6];
    const float* he       = (const float*)d_in[7];
    float* out = (float*)d_out;
    float* ws  = (float*)d_ws;

    float* Q  = ws + Q_OFF;
    unsigned short* Vb = (unsigned short*)(ws + V_OFF);

    k_qkv_mfma<<<dim3(21, 32), 256, 0, stream>>>(x, wqkv_w, wqkv_b, he, Q, Vb);
    k_attn_out<<<dim3(14, 16), 512, 0, stream>>>(x, Q, wk_w, msk, Vb,
                                                 fanout_w, fanout_b, out);
}

// Round 2
// 114.752 us; speedup vs baseline: 1.0913x; 1.0498x over previous
//
#include <hip/hip_runtime.h>
#include <math.h>

#define Bq 16
#define Tq 81
#define Dq 128
#define Hq 8
#define BT (Bq*Tq)          // 1296
#define BTD (Bq*Tq*Dq)      // 165888 (out region 0)
#define PS 84               // padded s-stride of P rows in LDS
// ws layout (floats). Q: [b][h][t][d] f32; V: [b][h][s][d] bf16 in V_OFF.
#define P_SZ   (Bq*Tq*Hq*PS)
#define QV_SZ  (BT*Hq*Dq)
#define P_OFF  0
#define Q_OFF  (P_OFF + P_SZ)
#define V_OFF  (Q_OFF + QV_SZ)

#define LSTR 136            // k_qkv LDS row stride (ushorts): 16B-aligned rows

#define TCH 3               // t-rows per k23 block (81 = 27*3, no tail)
#define NCH 27

typedef __attribute__((ext_vector_type(8))) short short8;
typedef __attribute__((ext_vector_type(4))) float f32x4;

__device__ __forceinline__ float l1_4(const float4 q, const float4 k) {
    return fabsf(q.x - k.x) + fabsf(q.y - k.y) + fabsf(q.z - k.z) + fabsf(q.w - k.w);
}
__device__ __forceinline__ int imin(int a, int b) { return a < b ? a : b; }
__device__ __forceinline__ unsigned short f2bf(float f) {   // RNE f32 -> bf16
    unsigned u = __float_as_uint(f);
    u += 0x7fffu + ((u >> 16) & 1u);
    return (unsigned short)(u >> 16);
}
__device__ __forceinline__ float bf2f(unsigned short s) {
    return __uint_as_float((unsigned)s << 16);
}

// ---------------------------------------------------------------------------
// K1: QKV GEMM via bf16 MFMA 16x16x32. grid (21, 32), 256 thr = 4 waves.
// Unchanged (verified).
// ---------------------------------------------------------------------------
__global__ __launch_bounds__(256) void k_qkv_mfma(
    const float* __restrict__ x, const float* __restrict__ wqkv,
    const float* __restrict__ bias, const float* __restrict__ he,
    float* __restrict__ Qo, unsigned short* __restrict__ Vb)
{
    __shared__ unsigned short xs[64 * LSTR];    // 17.4 KB
    __shared__ unsigned short wsh[64 * LSTR];   // 17.4 KB
    const int tid = threadIdx.x;
    const int w = tid >> 6, lane = tid & 63;
    const int ln = lane & 15, quad = lane >> 4;
    const int r0 = blockIdx.x * 64;               // m-row base (bx 0..20)
    const int n0 = blockIdx.y * 64;               // W-row base
    const int h  = blockIdx.y >> 2;
    const int isV = (blockIdx.y >> 1) & 1;
    const int c0 = (blockIdx.y & 1) * 64;

    #pragma unroll
    for (int i = 0; i < 8; ++i) {
        const int idx = tid + i * 256;            // 0..2047
        const int r = idx >> 5, c4 = idx & 31;
        const int gr = imin(r0 + r, BT - 1);      // clamp tail rows
        const float4 v = *(const float4*)(x + (size_t)gr * Dq + c4 * 4);
        ushort4 o;
        o.x = f2bf(v.x); o.y = f2bf(v.y); o.z = f2bf(v.z); o.w = f2bf(v.w);
        *(ushort4*)(&xs[r * LSTR + c4 * 4]) = o;

        const float4 vw = *(const float4*)(wqkv + (size_t)(n0 + r) * Dq + c4 * 4);
        ushort4 ow;
        ow.x = f2bf(vw.x); ow.y = f2bf(vw.y); ow.z = f2bf(vw.z); ow.w = f2bf(vw.w);
        *(ushort4*)(&wsh[r * LSTR + c4 * 4]) = ow;
    }
    __syncthreads();

    const unsigned short* xa = xs + (w * 16 + ln) * LSTR + quad * 8;
    const unsigned short* wb = wsh + ln * LSTR + quad * 8;

    f32x4 acc[4];
    #pragma unroll
    for (int i = 0; i < 4; ++i) acc[i] = (f32x4){0.f, 0.f, 0.f, 0.f};

    #pragma unroll
    for (int kb = 0; kb < Dq; kb += 32) {
        const short8 af = *(const short8*)(xa + kb);
        #pragma unroll
        for (int nt = 0; nt < 4; ++nt) {
            const short8 bf = *(const short8*)(wb + nt * 16 * LSTR + kb);
            acc[nt] = __builtin_amdgcn_mfma_f32_16x16x32_bf16(af, bf, acc[nt], 0, 0, 0);
        }
    }

    const float scale = isV ? he[h] : 1.0f;
    const int gm0 = r0 + w * 16 + quad * 4;
    #pragma unroll
    for (int nt = 0; nt < 4; ++nt) {
        const float bn = bias[n0 + nt * 16 + ln];
        #pragma unroll
        for (int r = 0; r < 4; ++r) {
            const int gm = gm0 + r;
            if (gm < BT) {
                const int bb = gm / 81, tt = gm - bb * 81;
                const size_t o =
                    (((size_t)bb * Hq + h) * Tq + tt) * Dq + c0 + nt * 16 + ln;
                const float val = (acc[nt][r] + bn) * scale;
                if (isV) Vb[o] = f2bf(val);
                else     Qo[o] = val;
            }
        }
    }
}

// ---------------------------------------------------------------------------
// K23: scores + softmax (+ap) + PV + gelu + fanout + residual.
// grid (27, 16) = (t-chunk3, b), block 512 = 8 waves; wave w = head w.
// R2 changes vs R1 (theory: k23 latency-bound at 1 block/CU + 63% lane
// efficiency in scores):
//  - TCH 6 -> 3 (81 = 27*3 exact; clamps removed), 432 blocks.
//  - LDS 84.6 -> 65.9 KB via overlay (xl/Ql/wkl dead after B -> bo/zs)
//    => 2 blocks/CU, 4 waves/SIMD.
//  - Q tile + wk staged in LDS (phase A): score inner loop is all-LDS.
//  - tail s in [64,81): 51 dedicated (t,s) cells on lanes 0..50 (one short
//    pass) instead of a fully-padded 64-lane second half; scores staged
//    through Pl for the softmax.
// smem overlay (floats):
//   [0,10368)=xl  [10368,13440)=Ql  [13440,14464)=wkl     (phases A..C)
//   [0,3072)=bo   [4096,4480)=zs                          (phases D..F)
// ---------------------------------------------------------------------------
__global__ __launch_bounds__(512) void k_attn_out(
    const float* __restrict__ x, const float* __restrict__ Q,
    const float* __restrict__ wk, const float* __restrict__ msk,
    const unsigned short* __restrict__ Vb, const float* __restrict__ fw,
    const float* __restrict__ fb, float* __restrict__ out)
{
    __shared__ float smem[14464];            // 57.9 KB (overlaid)
    __shared__ float Pl[Hq][TCH][PS];        // 8.06 KB
    float* const xl  = smem;                 // [81][128], granule-swizzled
    float* const Ql  = smem + 10368;         // [8][3][128]
    float* const wkl = smem + 13440;         // [8][128]
    float* const bo  = smem;                 // [8*3][128] overlay
    float* const zs  = smem + 4096;          // [3][128]  overlay

    const int tid = threadIdx.x;
    const int t0 = blockIdx.x * TCH, b = blockIdx.y;
    const int w = tid >> 6, lane = tid & 63;   // w = head

    // ---- Phase A: stage xl (swizzled) + Ql + wkl ----
    for (int idx = tid; idx < Tq * 32; idx += 512) {
        const int r = idx >> 5, g = idx & 31;
        const float4 v = *(const float4*)(x + (size_t)(b * Tq + r) * Dq + g * 4);
        *(float4*)(&xl[r * Dq + ((g ^ (r & 7)) << 2)]) = v;
    }
    for (int idx = tid; idx < Hq * TCH * 32; idx += 512) {   // 768 float4
        const int row = idx >> 5, g = idx & 31;              // row = h*3+i
        const int h = row / TCH, i = row - h * TCH;
        const float4 v =
            *(const float4*)(Q + (((size_t)b * Hq + h) * Tq + t0 + i) * Dq + g * 4);
        *(float4*)(&Ql[row * Dq + g * 4]) = v;
    }
    if (tid < 256) {                                         // 8*128 floats
        const float4 v = *(const float4*)(wk + tid * 4);
        *(float4*)(&wkl[tid * 4]) = v;
    }
    __syncthreads();

    // ---- Phase B: L1-distance scores, all-LDS operands ----
    const float* wkw = wkl + w * Dq;
    const float* qb  = Ql + w * TCH * Dq;
    float acc0[TCH];
    #pragma unroll
    for (int i = 0; i < TCH; ++i) acc0[i] = 0.f;
    {   // main: s = lane (0..63), all 3 t-rows
        const int s = lane;
        #pragma unroll 2
        for (int g = 0; g < 32; ++g) {
            const float4 wv = *(const float4*)(wkw + g * 4);          // bcast
            float4 k0 = *(const float4*)(&xl[s * Dq + ((g ^ (s & 7)) << 2)]);
            k0.x *= wv.x; k0.y *= wv.y; k0.z *= wv.z; k0.w *= wv.w;
            #pragma unroll
            for (int i = 0; i < TCH; ++i) {
                const float4 qv = *(const float4*)(qb + i * Dq + g * 4); // bcast
                acc0[i] += l1_4(qv, k0);
            }
        }
    }
    const float ns = -0.08838834764831845f;   // -1/sqrt(128)
    {   // tail: 51 cells (t, s=64+j), lanes 0..50
        if (lane < TCH * 17) {
            const int tt = lane / 17, j = lane - tt * 17;
            const int s = 64 + j;
            float a = 0.f;
            #pragma unroll 2
            for (int g = 0; g < 32; ++g) {
                const float4 wv = *(const float4*)(wkw + g * 4);
                float4 kv = *(const float4*)(&xl[s * Dq + ((g ^ (s & 7)) << 2)]);
                kv.x *= wv.x; kv.y *= wv.y; kv.z *= wv.z; kv.w *= wv.w;
                const float4 qv = *(const float4*)(qb + tt * Dq + g * 4);
                a += l1_4(qv, kv);
            }
            Pl[w][tt][s] = a * ns;            // stage raw tail scores
        }
    }
    __syncthreads();

    // ---- Phase C: wave softmax + P->LDS + fused ap (b==0) ----
    {
        const bool has1 = (lane < Tq - 64);   // 17 lanes own s=64..80
        const int s1 = 64 + lane;
        #pragma unroll
        for (int i = 0; i < TCH; ++i) {
            const float v0 = acc0[i] * ns;
            const float v1 = has1 ? Pl[w][i][s1] : -1e30f;
            float m = fmaxf(v0, v1);
            #pragma unroll
            for (int off = 32; off > 0; off >>= 1)
                m = fmaxf(m, __shfl_xor(m, off));
            const float e0 = __expf(v0 - m);
            const float e1 = has1 ? __expf(v1 - m) : 0.f;
            float ssum = e0 + e1;
            #pragma unroll
            for (int off = 32; off > 0; off >>= 1)
                ssum += __shfl_xor(ssum, off);
            const float rinv = 1.0f / ssum;
            const float* mrow = msk + ((size_t)w * Tq + (t0 + i)) * Tq;
            const float mv0 = mrow[lane];
            const float p0 = e0 * rinv * mv0;
            Pl[w][i][lane] = p0;
            if (b == 0)
                out[BTD + ((size_t)(t0 + i) * Tq + lane) * Hq + w] = p0 - 1.0f + mv0;
            if (has1) {
                const float mv1 = mrow[s1];
                const float p1 = e1 * rinv * mv1;
                Pl[w][i][s1] = p1;
                if (b == 0)
                    out[BTD + ((size_t)(t0 + i) * Tq + s1) * Hq + w] = p1 - 1.0f + mv1;
            }
        }
    }
    __syncthreads();

    // ---- Phase D: PV einsum, bf16 V, s blocked by 4 ----
    {
        const int d0 = lane * 2;
        float2 acc[TCH];
        #pragma unroll
        for (int i = 0; i < TCH; ++i) acc[i] = make_float2(0.f, 0.f);
        const unsigned short* vp = Vb + (((size_t)b * Hq + w) * Tq) * Dq + d0;
        for (int s4 = 0; s4 < 20; ++s4) {
            float4 p[TCH];
            #pragma unroll
            for (int t = 0; t < TCH; ++t)
                p[t] = *(const float4*)(&Pl[w][t][s4 * 4]);
            #pragma unroll
            for (int ss = 0; ss < 4; ++ss) {
                const int s = s4 * 4 + ss;
                const ushort2 uv = *(const ushort2*)(vp + (size_t)s * Dq);
                const float vx = bf2f(uv.x), vy = bf2f(uv.y);
                #pragma unroll
                for (int t = 0; t < TCH; ++t) {
                    const float pv = ((const float*)&p[t])[ss];
                    acc[t].x = fmaf(pv, vx, acc[t].x);
                    acc[t].y = fmaf(pv, vy, acc[t].y);
                }
            }
        }
        {   // tail s = 80
            const ushort2 uv = *(const ushort2*)(vp + (size_t)80 * Dq);
            const float vx = bf2f(uv.x), vy = bf2f(uv.y);
            #pragma unroll
            for (int t = 0; t < TCH; ++t) {
                const float pv = Pl[w][t][80];
                acc[t].x = fmaf(pv, vx, acc[t].x);
                acc[t].y = fmaf(pv, vy, acc[t].y);
            }
        }
        #pragma unroll
        for (int t = 0; t < TCH; ++t) {
            bo[(w * TCH + t) * Dq + d0]     = acc[t].x;
            bo[(w * TCH + t) * Dq + d0 + 1] = acc[t].y;
        }
    }
    __syncthreads();

    // ---- Phase E: 8-way head reduce + quick-gelu ----
    for (int idx = tid; idx < TCH * Dq; idx += 512) {   // 3t x 128d
        const int t = idx >> 7, d = idx & 127;
        float s = 0.f;
        #pragma unroll
        for (int ww = 0; ww < 8; ++ww) s += bo[(ww * TCH + t) * Dq + d];
        const float tt2 = s + 4.0f;
        const float sg = 1.0f / (1.0f + __expf(-1.702f * tt2));
        zs[t * Dq + d] = tt2 * sg - 4.0f;
    }
    __syncthreads();

    // ---- Phase F: fanout + bias + residual (384 threads, 1 row each) ----
    {
        const int n = tid & 127, tg = tid >> 7;   // tg 0..3
        if (tg < TCH) {
            const float* fwr = fw + (size_t)n * Dq;
            float a0 = 0.f;
            #pragma unroll 8
            for (int k4 = 0; k4 < 32; ++k4) {
                const float4 w4 = *(const float4*)(fwr + k4 * 4);
                const float4 z0 = *(const float4*)(&zs[tg * Dq + k4 * 4]);
                a0 += z0.x * w4.x + z0.y * w4.y + z0.z * w4.z + z0.w * w4.w;
            }
            const size_t o = ((size_t)b * Tq + t0 + tg) * Dq + n;
            out[o] = x[o] + a0 + fb[n];
        }
    }
}

extern "C" void kernel_launch(void* const* d_in, const int* in_sizes, int n_in,
                              void* d_out, int out_size, void* d_ws, size_t ws_size,
                              hipStream_t stream) {
    const float* x        = (const float*)d_in[0];
    const float* msk      = (const float*)d_in[1];
    const float* wqkv_w   = (const float*)d_in[2];
    const float* wqkv_b   = (const float*)d_in[3];
    const float* wk_w     = (const float*)d_in[4];
    const float* fanout_w = (const float*)d_in[5];
    const float* fanout_b = (const float*)d_in[6];
    const float* he       = (const float*)d_in[7];
    float* out = (float*)d_out;
    float* ws  = (float*)d_ws;

    float* Q  = ws + Q_OFF;
    unsigned short* Vb = (unsigned short*)(ws + V_OFF);

    k_qkv_mfma<<<dim3(21, 32), 256, 0, stream>>>(x, wqkv_w, wqkv_b, he, Q, Vb);
    k_attn_out<<<dim3(NCH, 16), 512, 0, stream>>>(x, Q, wk_w, msk, Vb,
                                                  fanout_w, fanout_b, out);
}